// Round 2
// baseline (364.756 us; speedup 1.0000x reference)
//
#include <hip/hip_runtime.h>
#include <hip/hip_bf16.h>

// RBF kernel: out[i][j] = exp(-gamma * max(0, x2[i] + y2[j] - 2*dot(X[i], Y[j])))
// N = M = 8192, D = 512.  bf16 MFMA GEMM (no f32 MFMA on CDNA4), exact f32 row
// norms, fused epilogue.  256x256 tile, BK=64, 8 waves, 4-phase interleave with
// counted vmcnt (T3+T4), LDS XOR swizzle (T2), setprio around MFMA (T5).

#define NROWS 8192
#define D_DIM 512
#define BM 256
#define BN 256
#define BK 64
#define NKT (D_DIM / BK)  // 8 K-tiles

using bf16x8 = __attribute__((ext_vector_type(8))) short;  // 8 bf16 (4 VGPRs)
using f32x4  = __attribute__((ext_vector_type(4))) float;  // MFMA accumulator

__device__ inline unsigned pack2_bf16(float a, float b) {
    unsigned ua = __builtin_bit_cast(unsigned, a);
    unsigned ub = __builtin_bit_cast(unsigned, b);
    ua = (ua + 0x7fffu + ((ua >> 16) & 1u)) >> 16;
    ub = (ub + 0x7fffu + ((ub >> 16) & 1u)) >> 16;
    return ua | (ub << 16);
}

// One wave per row: convert 512 f32 -> bf16, exact f32 sum of squares.
__global__ __launch_bounds__(64) void prep_kernel(const float* __restrict__ src,
                                                  unsigned short* __restrict__ dst,
                                                  float* __restrict__ norms) {
    const int row  = blockIdx.x;
    const int lane = threadIdx.x;
    const float4* s = reinterpret_cast<const float4*>(src) + (size_t)row * (D_DIM / 4);
    float4 v0 = s[lane * 2];
    float4 v1 = s[lane * 2 + 1];
    float ss = v0.x * v0.x + v0.y * v0.y + v0.z * v0.z + v0.w * v0.w +
               v1.x * v1.x + v1.y * v1.y + v1.z * v1.z + v1.w * v1.w;
    uint4 p;
    p.x = pack2_bf16(v0.x, v0.y);
    p.y = pack2_bf16(v0.z, v0.w);
    p.z = pack2_bf16(v1.x, v1.y);
    p.w = pack2_bf16(v1.z, v1.w);
    reinterpret_cast<uint4*>(dst + (size_t)row * D_DIM)[lane] = p;
    #pragma unroll
    for (int off = 32; off; off >>= 1) ss += __shfl_down(ss, off);
    if (lane == 0) norms[row] = ss;
}

__device__ inline void gload_lds16(const unsigned short* g, unsigned short* l) {
    __builtin_amdgcn_global_load_lds(
        (const __attribute__((address_space(1))) void*)g,
        (__attribute__((address_space(3))) void*)l, 16, 0, 0);
}

__global__ __launch_bounds__(512, 2) void rbf_gemm(
    const unsigned short* __restrict__ Xb, const unsigned short* __restrict__ Yb,
    const float* __restrict__ x2, const float* __restrict__ y2,
    const float* __restrict__ gptr, float* __restrict__ out) {
    // Double-buffered tiles, 128 KiB total (gfx950: 160 KiB/CU).
    __shared__ unsigned short sA[2][BM * BK];  // 2 x 32 KB
    __shared__ unsigned short sB[2][BN * BK];  // 2 x 32 KB

    // XCD swizzle: 1024 blocks % 8 == 0 -> simple bijective form.
    const int bid  = blockIdx.x;
    const int swz  = (bid & 7) * 128 + (bid >> 3);
    const int brow = swz >> 5;   // 32 tiles per dim
    const int bcol = swz & 31;

    const int tid  = threadIdx.x;
    const int lane = tid & 63;
    const int wid  = tid >> 6;   // 0..7
    const int wr   = wid >> 2;   // 0..1  (wave M quadrant: 128 rows)
    const int wc   = wid & 3;    // 0..3  (wave N quadrant: 64 cols)

    // ---- staging addressing (pre-swizzled global source, linear LDS dest) ----
    // LDS[row][slot16] holds G[row][slot16 ^ (row&7)]; thread writes slot tid&7
    // at row (tid>>3) (+64 for round 1), so its source slot = (tid&7)^((tid>>3)&7).
    const int srow = tid >> 3;                                  // 0..63
    const int scol = ((tid & 7) ^ ((tid >> 3) & 7)) * 8;        // element offset
    const unsigned short* gA0 = Xb + (size_t)(brow * BM) * D_DIM + scol;
    const unsigned short* gB0 = Yb + (size_t)(bcol * BN) * D_DIM + scol;

    // ---- fragment read addressing (same XOR on the read side) ----
    const int lr = lane & 15;   // row within fragment
    const int kg = lane >> 4;   // k-group 0..3
    const int lx = lane & 7;    // row&7 == lane&7 for all fragment rows
    const int sl0 = ((0 * 4 + kg) ^ lx) * 8;  // k-half 0 slot (elements)
    const int sl1 = ((1 * 4 + kg) ^ lx) * 8;  // k-half 1 slot
    const int aBase = (wr * 128 + lr) * BK;
    const int bBase = (wc * 64 + lr) * BK;

    f32x4 acc[8][4] = {};
    bf16x8 av[4][2], bv[4][2];

    // quarter q: 0 -> B rows 0..127, 1 -> B rows 128..255, 2 -> A 0..127, 3 -> A 128..255
    auto STAGE = [&](int d, int kt, int q) {
        const bool isA = q >= 2;
        const int half = q & 1;
        const unsigned short* g = (isA ? gA0 : gB0) +
            (size_t)(half * 128 + srow) * D_DIM + kt * BK;
        unsigned short* l = (isA ? sA[d] : sB[d]) +
            (half * 128 + srow) * BK + (tid & 7) * 8;
        gload_lds16(g, l);
        gload_lds16(g + 64 * D_DIM, l + 64 * BK);
    };

    #define LDF(p) (*reinterpret_cast<const bf16x8*>(p))
    #define MFMA(a, b, c) __builtin_amdgcn_mfma_f32_16x16x32_bf16(a, b, c, 0, 0, 0)

    // Prologue: stage K-tile 0 into buffer 0 (8 in-flight loads per wave).
    #pragma unroll
    for (int q = 0; q < 4; ++q) STAGE(0, 0, q);

    for (int t = 0; t < NKT; ++t) {
        const int c = t & 1, d = c ^ 1;
        const bool pre = (t + 1 < NKT);
        const unsigned short* A = sA[c];
        const unsigned short* B = sB[c];

        // ---------- phase 0: quadrant m0-3 x n0-1 ----------
        if (pre) STAGE(d, t + 1, 0);
        if (pre) asm volatile("s_waitcnt vmcnt(2)" ::: "memory");
        else     asm volatile("s_waitcnt vmcnt(0)" ::: "memory");
        asm volatile("s_barrier" ::: "memory");  // publish buf c (all waves' loads done)
        #pragma unroll
        for (int m = 0; m < 4; ++m) {
            av[m][0] = LDF(A + aBase + m * 16 * BK + sl0);
            av[m][1] = LDF(A + aBase + m * 16 * BK + sl1);
        }
        #pragma unroll
        for (int n = 0; n < 2; ++n) {
            bv[n][0] = LDF(B + bBase + n * 16 * BK + sl0);
            bv[n][1] = LDF(B + bBase + n * 16 * BK + sl1);
        }
        __builtin_amdgcn_s_setprio(1);
        #pragma unroll
        for (int m = 0; m < 4; ++m)
            #pragma unroll
            for (int n = 0; n < 2; ++n) {
                acc[m][n] = MFMA(av[m][0], bv[n][0], acc[m][n]);
                acc[m][n] = MFMA(av[m][1], bv[n][1], acc[m][n]);
            }
        __builtin_amdgcn_s_setprio(0);
        asm volatile("s_barrier" ::: "memory");

        // ---------- phase 1: quadrant m0-3 x n2-3 ----------
        if (pre) STAGE(d, t + 1, 1);
        #pragma unroll
        for (int n = 2; n < 4; ++n) {
            bv[n][0] = LDF(B + bBase + n * 16 * BK + sl0);
            bv[n][1] = LDF(B + bBase + n * 16 * BK + sl1);
        }
        __builtin_amdgcn_s_setprio(1);
        #pragma unroll
        for (int m = 0; m < 4; ++m)
            #pragma unroll
            for (int n = 2; n < 4; ++n) {
                acc[m][n] = MFMA(av[m][0], bv[n][0], acc[m][n]);
                acc[m][n] = MFMA(av[m][1], bv[n][1], acc[m][n]);
            }
        __builtin_amdgcn_s_setprio(0);
        asm volatile("s_barrier" ::: "memory");

        // ---------- phase 2: quadrant m4-7 x n0-1 ----------
        if (pre) STAGE(d, t + 1, 2);
        #pragma unroll
        for (int m = 0; m < 4; ++m) {
            av[m][0] = LDF(A + aBase + (m + 4) * 16 * BK + sl0);
            av[m][1] = LDF(A + aBase + (m + 4) * 16 * BK + sl1);
        }
        __builtin_amdgcn_s_setprio(1);
        #pragma unroll
        for (int m = 0; m < 4; ++m)
            #pragma unroll
            for (int n = 0; n < 2; ++n) {
                acc[m + 4][n] = MFMA(av[m][0], bv[n][0], acc[m + 4][n]);
                acc[m + 4][n] = MFMA(av[m][1], bv[n][1], acc[m + 4][n]);
            }
        __builtin_amdgcn_s_setprio(0);
        asm volatile("s_barrier" ::: "memory");

        // ---------- phase 3: quadrant m4-7 x n2-3 ----------
        if (pre) STAGE(d, t + 1, 3);
        __builtin_amdgcn_s_setprio(1);
        #pragma unroll
        for (int m = 0; m < 4; ++m)
            #pragma unroll
            for (int n = 2; n < 4; ++n) {
                acc[m + 4][n] = MFMA(av[m][0], bv[n][0], acc[m + 4][n]);
                acc[m + 4][n] = MFMA(av[m][1], bv[n][1], acc[m + 4][n]);
            }
        __builtin_amdgcn_s_setprio(0);
        asm volatile("s_barrier" ::: "memory");  // read-complete: buf c free to overwrite
    }

    // Epilogue. C/D layout: col = lane&15, row = (lane>>4)*4 + reg  [m89]
    const float g = *gptr;
    const int rbase = brow * BM + wr * 128 + (kg << 2);
    const int cbase = bcol * BN + wc * 64 + lr;

    float yv[4];
    #pragma unroll
    for (int n = 0; n < 4; ++n) yv[n] = y2[cbase + n * 16];

    #pragma unroll
    for (int m = 0; m < 8; ++m) {
        #pragma unroll
        for (int r = 0; r < 4; ++r) {
            const float xr = x2[rbase + m * 16 + r];
            const size_t ro = (size_t)(rbase + m * 16 + r) * NROWS + cbase;
            #pragma unroll
            for (int n = 0; n < 4; ++n) {
                float sq = fmaxf(xr + yv[n] - 2.0f * acc[m][n][r], 0.0f);
                out[ro + n * 16] = __expf(-g * sq);
            }
        }
    }
}

extern "C" void kernel_launch(void* const* d_in, const int* in_sizes, int n_in,
                              void* d_out, int out_size, void* d_ws, size_t ws_size,
                              hipStream_t stream) {
    const float* X = (const float*)d_in[0];
    const float* Y = (const float*)d_in[1];
    const float* gamma = (const float*)d_in[2];
    float* out = (float*)d_out;

    unsigned short* Xb = (unsigned short*)d_ws;                  // 8 MB
    unsigned short* Yb = Xb + (size_t)NROWS * D_DIM;             // 8 MB
    float* x2 = (float*)(Yb + (size_t)NROWS * D_DIM);            // 32 KB
    float* y2 = x2 + NROWS;                                      // 32 KB

    prep_kernel<<<NROWS, 64, 0, stream>>>(X, Xb, x2);
    prep_kernel<<<NROWS, 64, 0, stream>>>(Y, Yb, y2);

    const int grid = (NROWS / BM) * (NROWS / BN);  // 1024
    rbf_gemm<<<grid, 512, 0, stream>>>(Xb, Yb, x2, y2, gamma, out);
}

// Round 4
// 355.773 us; speedup vs baseline: 1.0252x; 1.0252x over previous
//
#include <hip/hip_runtime.h>
#include <hip/hip_bf16.h>

// RBF kernel: out[i][j] = exp(-gamma * max(0, x2[i] + y2[j] - 2*dot(X[i], Y[j])))
// N = M = 8192, D = 512.  bf16 MFMA GEMM, exact f32 row norms, fused epilogue.
// 256x256 tile, BK=64, 8 waves (2Mx4N), 4 phases/K-tile:
//   {ds_read frags -> STAGE one region of next tile -> counted vmcnt -> barrier
//    -> setprio(1) 16 MFMA setprio(0)}
// Regions (Ae/Ao/Be/Bo) aligned to collective phase reads; >=3 phases of
// prefetch slack; vmcnt never drains to 0 until the last tile (T3+T4).
// LDS XOR swizzle via pre-swizzled global source (T2).

#define NROWS 8192
#define D_DIM 512
#define BM 256
#define BN 256
#define BK 64
#define NKT (D_DIM / BK)  // 8 K-tiles

using bf16x8 = __attribute__((ext_vector_type(8))) short;
using f32x4  = __attribute__((ext_vector_type(4))) float;

__device__ inline unsigned pack2_bf16(float a, float b) {
    unsigned ua = __builtin_bit_cast(unsigned, a);
    unsigned ub = __builtin_bit_cast(unsigned, b);
    ua = (ua + 0x7fffu + ((ua >> 16) & 1u)) >> 16;
    ub = (ub + 0x7fffu + ((ub >> 16) & 1u)) >> 16;
    return ua | (ub << 16);
}

__global__ __launch_bounds__(64) void prep_kernel(const float* __restrict__ src,
                                                  unsigned short* __restrict__ dst,
                                                  float* __restrict__ norms) {
    const int row  = blockIdx.x;
    const int lane = threadIdx.x;
    const float4* s = reinterpret_cast<const float4*>(src) + (size_t)row * (D_DIM / 4);
    float4 v0 = s[lane * 2];
    float4 v1 = s[lane * 2 + 1];
    float ss = v0.x * v0.x + v0.y * v0.y + v0.z * v0.z + v0.w * v0.w +
               v1.x * v1.x + v1.y * v1.y + v1.z * v1.z + v1.w * v1.w;
    uint4 p;
    p.x = pack2_bf16(v0.x, v0.y);
    p.y = pack2_bf16(v0.z, v0.w);
    p.z = pack2_bf16(v1.x, v1.y);
    p.w = pack2_bf16(v1.z, v1.w);
    reinterpret_cast<uint4*>(dst + (size_t)row * D_DIM)[lane] = p;
    #pragma unroll
    for (int off = 32; off; off >>= 1) ss += __shfl_down(ss, off);
    if (lane == 0) norms[row] = ss;
}

__device__ inline void gload_lds16(const unsigned short* g, unsigned short* l) {
    __builtin_amdgcn_global_load_lds(
        (const __attribute__((address_space(1))) void*)g,
        (__attribute__((address_space(3))) void*)l, 16, 0, 0);
}

#define VMCNT(n) asm volatile("s_waitcnt vmcnt(" #n ")" ::: "memory")
#define BAR()    asm volatile("s_barrier" ::: "memory")
#define LDF(p)   (*reinterpret_cast<const bf16x8*>(p))
#define MFMA(a, b, c) __builtin_amdgcn_mfma_f32_16x16x32_bf16(a, b, c, 0, 0, 0)

__global__ __launch_bounds__(512, 2) void rbf_gemm(
    const unsigned short* __restrict__ Xb, const unsigned short* __restrict__ Yb,
    const float* __restrict__ x2, const float* __restrict__ y2,
    const float* __restrict__ gptr, float* __restrict__ out) {
    __shared__ unsigned short sA[2][BM * BK];  // 2 x 32 KB
    __shared__ unsigned short sB[2][BN * BK];  // 2 x 32 KB

    const int bid  = blockIdx.x;
    const int swz  = (bid & 7) * 128 + (bid >> 3);  // 1024 % 8 == 0: bijective
    const int brow = swz >> 5;
    const int bcol = swz & 31;

    const int tid  = threadIdx.x;
    const int lane = tid & 63;
    const int wid  = tid >> 6;
    const int wr   = wid >> 2;   // 0..1: wave M half (128 rows)
    const int wc   = wid & 3;    // 0..3: wave N strip (64 cols)

    // ---- staging addressing (pre-swizzled global src, linear LDS dest) ----
    const int slot  = tid & 7;
    const int srowA = tid >> 3;                               // 0..63
    const int srowB = ((tid >> 3) & 31) + ((tid >> 8) << 6);  // 0..31 / 64..95
    const int scol  = (slot ^ ((tid >> 3) & 7)) * 8;          // elements
    const unsigned short* gA = Xb + (size_t)(brow * BM + srowA) * D_DIM + scol;
    const unsigned short* gB = Yb + (size_t)(bcol * BN + srowB) * D_DIM + scol;
    const int loffA = srowA * BK + slot * 8;
    const int loffB = srowB * BK + slot * 8;

    // Ae: A rows {s, s+128}; Ao: {s+64, s+192}.  Be: B rows {sB, sB+128}
    // (sB in 0-31/64-95); Bo: {sB+32, sB+160}.  Matches collective phase reads.
    auto stA = [&](int d, int kt, int odd) {
        const unsigned short* g = gA + (size_t)(odd * 64) * D_DIM + kt * BK;
        unsigned short* l = sA[d] + odd * 64 * BK + loffA;
        gload_lds16(g, l);
        gload_lds16(g + 128 * D_DIM, l + 128 * BK);
    };
    auto stB = [&](int d, int kt, int odd) {
        const unsigned short* g = gB + (size_t)(odd * 32) * D_DIM + kt * BK;
        unsigned short* l = sB[d] + odd * 32 * BK + loffB;
        gload_lds16(g, l);
        gload_lds16(g + 128 * D_DIM, l + 128 * BK);
    };

    // ---- fragment read addressing (same XOR on the read side) ----
    const int lr  = lane & 15;
    const int kg  = lane >> 4;
    const int lx  = lane & 7;
    const int sl0 = ((0 * 4 + kg) ^ lx) * 8;
    const int sl1 = ((1 * 4 + kg) ^ lx) * 8;
    const int aBase = (wr * 128 + lr) * BK;
    const int bBase = (wc * 64 + lr) * BK;

    f32x4 acc[8][4] = {};
    bf16x8 av[4][2], bv[4][2];

    // Prologue: tile 0 -> buf 0, issue order Ae, Be, Bo, Ao (consumption order).
    stA(0, 0, 0); stB(0, 0, 0); stB(0, 0, 1); stA(0, 0, 1);
    VMCNT(4);  // Ae, Be landed; Bo, Ao may be in flight
    BAR();

    for (int t = 0; t < NKT; ++t) {
        const int c = t & 1, d = c ^ 1;
        const bool pre = (t + 1 < NKT);
        const unsigned short* A = sA[c];
        const unsigned short* B = sB[c];

        // ---- p0: reads Ae+Be frags; computes m0-3 x n0-1 ----
        #pragma unroll
        for (int m = 0; m < 4; ++m) {
            av[m][0] = LDF(A + aBase + m * 16 * BK + sl0);
            av[m][1] = LDF(A + aBase + m * 16 * BK + sl1);
        }
        #pragma unroll
        for (int n = 0; n < 2; ++n) {
            bv[n][0] = LDF(B + bBase + n * 16 * BK + sl0);
            bv[n][1] = LDF(B + bBase + n * 16 * BK + sl1);
        }
        if (pre) { stA(d, t + 1, 0); VMCNT(4); }  // cover t.Bo for p1
        else     { VMCNT(2); }
        BAR();
        __builtin_amdgcn_s_setprio(1);
        #pragma unroll
        for (int m = 0; m < 4; ++m)
            #pragma unroll
            for (int n = 0; n < 2; ++n) {
                acc[m][n] = MFMA(av[m][0], bv[n][0], acc[m][n]);
                acc[m][n] = MFMA(av[m][1], bv[n][1], acc[m][n]);
            }
        __builtin_amdgcn_s_setprio(0);

        // ---- p1: reads Bo frags; computes m0-3 x n2-3 ----
        #pragma unroll
        for (int n = 2; n < 4; ++n) {
            bv[n][0] = LDF(B + bBase + n * 16 * BK + sl0);
            bv[n][1] = LDF(B + bBase + n * 16 * BK + sl1);
        }
        if (pre) { stB(d, t + 1, 0); VMCNT(4); }  // cover t.Ao for p2
        else     { VMCNT(0); }
        BAR();
        __builtin_amdgcn_s_setprio(1);
        #pragma unroll
        for (int m = 0; m < 4; ++m)
            #pragma unroll
            for (int n = 2; n < 4; ++n) {
                acc[m][n] = MFMA(av[m][0], bv[n][0], acc[m][n]);
                acc[m][n] = MFMA(av[m][1], bv[n][1], acc[m][n]);
            }
        __builtin_amdgcn_s_setprio(0);

        // ---- p2: reads Ao frags; computes m4-7 x n0-1 ----
        #pragma unroll
        for (int m = 0; m < 4; ++m) {
            av[m][0] = LDF(A + aBase + (m + 4) * 16 * BK + sl0);
            av[m][1] = LDF(A + aBase + (m + 4) * 16 * BK + sl1);
        }
        if (pre) stB(d, t + 1, 1);
        BAR();  // p3 reads nothing; barrier keeps waves in lockstep
        __builtin_amdgcn_s_setprio(1);
        #pragma unroll
        for (int m = 0; m < 4; ++m)
            #pragma unroll
            for (int n = 0; n < 2; ++n) {
                acc[m + 4][n] = MFMA(av[m][0], bv[n][0], acc[m + 4][n]);
                acc[m + 4][n] = MFMA(av[m][1], bv[n][1], acc[m + 4][n]);
            }
        __builtin_amdgcn_s_setprio(0);

        // ---- p3: computes m4-7 x n2-3 ----
        if (pre) {
            stA(d, t + 1, 1);
            VMCNT(4);  // cover (t+1).Ae, (t+1).Be for next tile's p0
            BAR();
        }
        __builtin_amdgcn_s_setprio(1);
        #pragma unroll
        for (int m = 0; m < 4; ++m)
            #pragma unroll
            for (int n = 2; n < 4; ++n) {
                acc[m + 4][n] = MFMA(av[m][0], bv[n][0], acc[m + 4][n]);
                acc[m + 4][n] = MFMA(av[m][1], bv[n][1], acc[m + 4][n]);
            }
        __builtin_amdgcn_s_setprio(0);
    }

    // Epilogue. C/D layout: col = lane&15, row = (lane>>4)*4 + reg  [m89]
    const float g = *gptr;
    const int rbase = brow * BM + wr * 128 + (kg << 2);
    const int cbase = bcol * BN + wc * 64 + lr;

    float yv[4];
    #pragma unroll
    for (int n = 0; n < 4; ++n) yv[n] = y2[cbase + n * 16];

    #pragma unroll
    for (int m = 0; m < 8; ++m) {
        #pragma unroll
        for (int r = 0; r < 4; ++r) {
            const float xr = x2[rbase + m * 16 + r];
            const size_t ro = (size_t)(rbase + m * 16 + r) * NROWS + cbase;
            #pragma unroll
            for (int n = 0; n < 4; ++n) {
                float sq = fmaxf(xr + yv[n] - 2.0f * acc[m][n][r], 0.0f);
                __builtin_nontemporal_store(__expf(-g * sq), &out[ro + n * 16]);
            }
        }
    }
}

extern "C" void kernel_launch(void* const* d_in, const int* in_sizes, int n_in,
                              void* d_out, int out_size, void* d_ws, size_t ws_size,
                              hipStream_t stream) {
    const float* X = (const float*)d_in[0];
    const float* Y = (const float*)d_in[1];
    const float* gamma = (const float*)d_in[2];
    float* out = (float*)d_out;

    unsigned short* Xb = (unsigned short*)d_ws;                  // 8 MB
    unsigned short* Yb = Xb + (size_t)NROWS * D_DIM;             // 8 MB
    float* x2 = (float*)(Yb + (size_t)NROWS * D_DIM);            // 32 KB
    float* y2 = x2 + NROWS;                                      // 32 KB

    prep_kernel<<<NROWS, 64, 0, stream>>>(X, Xb, x2);
    prep_kernel<<<NROWS, 64, 0, stream>>>(Y, Yb, y2);

    const int grid = (NROWS / BM) * (NROWS / BN);  // 1024
    rbf_gemm<<<grid, 512, 0, stream>>>(Xb, Yb, x2, y2, gamma, out);
}

// Round 5
// 355.446 us; speedup vs baseline: 1.0262x; 1.0009x over previous
//
#include <hip/hip_runtime.h>
#include <hip/hip_bf16.h>

// RBF kernel: out[i][j] = exp(-gamma * max(0, x2[i] + y2[j] - 2*dot(X[i], Y[j])))
// N = M = 8192, D = 512.  bf16 MFMA GEMM, exact f32 row norms, fused epilogue.
// m201-faithful schedule: 256x256 tile, BK=64, 8 waves (2Mx4N), 4 phases/K-tile,
// TWO barriers per phase, stage stream 7 half-tiles ahead, ONE counted vmcnt(6)
// per K-tile (drain only before the final tile).  T2 swizzle via pre-swizzled
// global source; T5 setprio around each 16-MFMA cluster.

#define NROWS 8192
#define D_DIM 512
#define BM 256
#define BN 256
#define BK 64
#define NKT (D_DIM / BK)  // 8 K-tiles; 32 half-tiles total

using bf16x8 = __attribute__((ext_vector_type(8))) short;
using f32x4  = __attribute__((ext_vector_type(4))) float;

__device__ inline unsigned pack2_bf16(float a, float b) {
    unsigned ua = __builtin_bit_cast(unsigned, a);
    unsigned ub = __builtin_bit_cast(unsigned, b);
    ua = (ua + 0x7fffu + ((ua >> 16) & 1u)) >> 16;
    ub = (ub + 0x7fffu + ((ub >> 16) & 1u)) >> 16;
    return ua | (ub << 16);
}

// One wave per row (X rows then Y rows): f32 -> bf16 + exact f32 row norm.
__global__ __launch_bounds__(64) void prep_all(const float* __restrict__ X,
                                               const float* __restrict__ Y,
                                               unsigned short* __restrict__ Xb,
                                               unsigned short* __restrict__ Yb,
                                               float* __restrict__ x2,
                                               float* __restrict__ y2) {
    const int bid  = blockIdx.x;
    const bool isY = bid >= NROWS;
    const int row  = isY ? bid - NROWS : bid;
    const float* src = isY ? Y : X;
    unsigned short* dst = isY ? Yb : Xb;
    float* nrm = isY ? y2 : x2;

    const int lane = threadIdx.x;
    const float4* s = reinterpret_cast<const float4*>(src) + (size_t)row * (D_DIM / 4);
    float4 v0 = s[lane * 2];
    float4 v1 = s[lane * 2 + 1];
    float ss = v0.x * v0.x + v0.y * v0.y + v0.z * v0.z + v0.w * v0.w +
               v1.x * v1.x + v1.y * v1.y + v1.z * v1.z + v1.w * v1.w;
    uint4 p;
    p.x = pack2_bf16(v0.x, v0.y);
    p.y = pack2_bf16(v0.z, v0.w);
    p.z = pack2_bf16(v1.x, v1.y);
    p.w = pack2_bf16(v1.z, v1.w);
    reinterpret_cast<uint4*>(dst + (size_t)row * D_DIM)[lane] = p;
    #pragma unroll
    for (int off = 32; off; off >>= 1) ss += __shfl_down(ss, off);
    if (lane == 0) nrm[row] = ss;
}

__device__ inline void gload_lds16(const unsigned short* g, unsigned short* l) {
    __builtin_amdgcn_global_load_lds(
        (const __attribute__((address_space(1))) void*)g,
        (__attribute__((address_space(3))) void*)l, 16, 0, 0);
}

#define VMCNT(n) asm volatile("s_waitcnt vmcnt(" #n ")" ::: "memory")
#define BAR()    asm volatile("s_barrier" ::: "memory")
#define LDF(p)   (*reinterpret_cast<const bf16x8*>(p))
#define MFMA(a, b, c) __builtin_amdgcn_mfma_f32_16x16x32_bf16(a, b, c, 0, 0, 0)

__global__ __launch_bounds__(512, 2) void rbf_gemm(
    const unsigned short* __restrict__ Xb, const unsigned short* __restrict__ Yb,
    const float* __restrict__ x2, const float* __restrict__ y2,
    const float* __restrict__ gptr, float* __restrict__ out) {
    __shared__ unsigned short sA[2][BM * BK];  // 2 x 32 KB
    __shared__ unsigned short sB[2][BN * BK];  // 2 x 32 KB  (128 KB: 1 block/CU)

    const int bid  = blockIdx.x;
    const int swz  = (bid & 7) * 128 + (bid >> 3);  // 1024 % 8 == 0: bijective
    const int brow = swz >> 5;
    const int bcol = swz & 31;

    const int tid  = threadIdx.x;
    const int lane = tid & 63;
    const int wid  = tid >> 6;
    const int wr   = wid >> 2;   // 0..1: wave M half (128 rows)
    const int wc   = wid & 3;    // 0..3: wave N strip (64 cols)

    // ---- staging addressing (pre-swizzled global src, linear LDS dest) ----
    const int slot  = tid & 7;
    const int srowA = tid >> 3;                               // 0..63
    const int srowB = ((tid >> 3) & 31) + ((tid >> 8) << 6);  // 0..31 / 64..95
    const int scol  = (slot ^ ((tid >> 3) & 7)) * 8;          // elements
    const unsigned short* gA = Xb + (size_t)(brow * BM + srowA) * D_DIM + scol;
    const unsigned short* gB = Yb + (size_t)(bcol * BN + srowB) * D_DIM + scol;
    const int loffA = srowA * BK + slot * 8;
    const int loffB = srowB * BK + slot * 8;

    // Half-tile regions (match collective phase reads):
    //   ht0 = Ae: A rows {s, s+128}         (read at p0)
    //   ht1 = Be: B rows {sB, sB+128}       (read at p0)
    //   ht2 = Bo: B rows {sB+32, sB+160}    (read at p1)
    //   ht3 = Ao: A rows {s+64, s+192}      (read at p2)
    auto stA = [&](int d, int kt, int odd) {
        const unsigned short* g = gA + (size_t)(odd * 64) * D_DIM + kt * BK;
        unsigned short* l = sA[d] + odd * 64 * BK + loffA;
        gload_lds16(g, l);
        gload_lds16(g + 128 * D_DIM, l + 128 * BK);
    };
    auto stB = [&](int d, int kt, int odd) {
        const unsigned short* g = gB + (size_t)(odd * 32) * D_DIM + kt * BK;
        unsigned short* l = sB[d] + odd * 32 * BK + loffB;
        gload_lds16(g, l);
        gload_lds16(g + 128 * D_DIM, l + 128 * BK);
    };
    // Global half-tile stream: s = 4*kt + ht; staged in consumption order.
    auto STAGE_S = [&](int s) {
        if (s >= 4 * NKT) return;
        const int kt = s >> 2, ht = s & 3, d = kt & 1;
        if      (ht == 0) stA(d, kt, 0);
        else if (ht == 1) stB(d, kt, 0);
        else if (ht == 2) stB(d, kt, 1);
        else              stA(d, kt, 1);
    };

    // ---- fragment read addressing (same XOR on the read side) ----
    const int lr  = lane & 15;
    const int kg  = lane >> 4;
    const int lx  = lane & 7;
    const int sl0 = ((0 * 4 + kg) ^ lx) * 8;
    const int sl1 = ((1 * 4 + kg) ^ lx) * 8;
    const int aBase = (wr * 128 + lr) * BK;
    const int bBase = (wc * 64 + lr) * BK;

    f32x4 acc[8][4] = {};
    bf16x8 av[4][2], bv[4][2];

    // Prologue: stage 7 half-tiles (KT0 fully + KT1's Ae,Be,Bo), counted wait.
    #pragma unroll
    for (int s = 0; s < 7; ++s) STAGE_S(s);
    VMCNT(6);  // 14 issued, <=6 outstanding -> KT0's 8 loads landed
    BAR();

    for (int t = 0; t < NKT; ++t) {
        const int c = t & 1;
        const unsigned short* A = sA[c];
        const unsigned short* B = sB[c];
        const int sbase = 7 + 4 * t;  // stage stream position at p0

        // ---- p0: reads Ae+Be; stages KT(t+1).Ao; computes m0-3 x n0-1 ----
        #pragma unroll
        for (int m = 0; m < 4; ++m) {
            av[m][0] = LDF(A + aBase + m * 16 * BK + sl0);
            av[m][1] = LDF(A + aBase + m * 16 * BK + sl1);
        }
        #pragma unroll
        for (int n = 0; n < 2; ++n) {
            bv[n][0] = LDF(B + bBase + n * 16 * BK + sl0);
            bv[n][1] = LDF(B + bBase + n * 16 * BK + sl1);
        }
        STAGE_S(sbase);
        BAR();
        __builtin_amdgcn_s_setprio(1);
        #pragma unroll
        for (int m = 0; m < 4; ++m)
            #pragma unroll
            for (int n = 0; n < 2; ++n) {
                acc[m][n] = MFMA(av[m][0], bv[n][0], acc[m][n]);
                acc[m][n] = MFMA(av[m][1], bv[n][1], acc[m][n]);
            }
        __builtin_amdgcn_s_setprio(0);
        BAR();

        // ---- p1: reads Bo; stages KT(t+2).Ae; computes m0-3 x n2-3 ----
        #pragma unroll
        for (int n = 2; n < 4; ++n) {
            bv[n][0] = LDF(B + bBase + n * 16 * BK + sl0);
            bv[n][1] = LDF(B + bBase + n * 16 * BK + sl1);
        }
        STAGE_S(sbase + 1);
        BAR();
        __builtin_amdgcn_s_setprio(1);
        #pragma unroll
        for (int m = 0; m < 4; ++m)
            #pragma unroll
            for (int n = 2; n < 4; ++n) {
                acc[m][n] = MFMA(av[m][0], bv[n][0], acc[m][n]);
                acc[m][n] = MFMA(av[m][1], bv[n][1], acc[m][n]);
            }
        __builtin_amdgcn_s_setprio(0);
        BAR();

        // ---- p2: reads Ao; stages KT(t+2).Be; computes m4-7 x n0-1 ----
        #pragma unroll
        for (int m = 0; m < 4; ++m) {
            av[m][0] = LDF(A + aBase + (m + 4) * 16 * BK + sl0);
            av[m][1] = LDF(A + aBase + (m + 4) * 16 * BK + sl1);
        }
        STAGE_S(sbase + 2);
        BAR();
        __builtin_amdgcn_s_setprio(1);
        #pragma unroll
        for (int m = 0; m < 4; ++m)
            #pragma unroll
            for (int n = 0; n < 2; ++n) {
                acc[m + 4][n] = MFMA(av[m][0], bv[n][0], acc[m + 4][n]);
                acc[m + 4][n] = MFMA(av[m][1], bv[n][1], acc[m + 4][n]);
            }
        __builtin_amdgcn_s_setprio(0);
        BAR();

        // ---- p3: stages KT(t+2).Bo; ONE counted vmcnt per tile ----
        STAGE_S(sbase + 3);
        if (t < NKT - 2)       VMCNT(6);  // newest 6 = KT(t+2).{Ae,Be,Bo} -> KT(t+1) landed
        else if (t == NKT - 2) VMCNT(0);  // drain for the final tile
        BAR();
        __builtin_amdgcn_s_setprio(1);
        #pragma unroll
        for (int m = 0; m < 4; ++m)
            #pragma unroll
            for (int n = 2; n < 4; ++n) {
                acc[m + 4][n] = MFMA(av[m][0], bv[n][0], acc[m + 4][n]);
                acc[m + 4][n] = MFMA(av[m][1], bv[n][1], acc[m + 4][n]);
            }
        __builtin_amdgcn_s_setprio(0);
        BAR();
    }

    // Epilogue. C/D layout: col = lane&15, row = (lane>>4)*4 + reg  [m89]
    const float g = *gptr;
    const int rbase = brow * BM + wr * 128 + (kg << 2);
    const int cbase = bcol * BN + wc * 64 + lr;

    float yv[4];
    #pragma unroll
    for (int n = 0; n < 4; ++n) yv[n] = y2[cbase + n * 16];

    #pragma unroll
    for (int m = 0; m < 8; ++m) {
        #pragma unroll
        for (int r = 0; r < 4; ++r) {
            const float xr = x2[rbase + m * 16 + r];
            const size_t ro = (size_t)(rbase + m * 16 + r) * NROWS + cbase;
            #pragma unroll
            for (int n = 0; n < 4; ++n) {
                float sq = fmaxf(xr + yv[n] - 2.0f * acc[m][n][r], 0.0f);
                __builtin_nontemporal_store(__expf(-g * sq), &out[ro + n * 16]);
            }
        }
    }
}

extern "C" void kernel_launch(void* const* d_in, const int* in_sizes, int n_in,
                              void* d_out, int out_size, void* d_ws, size_t ws_size,
                              hipStream_t stream) {
    const float* X = (const float*)d_in[0];
    const float* Y = (const float*)d_in[1];
    const float* gamma = (const float*)d_in[2];
    float* out = (float*)d_out;

    unsigned short* Xb = (unsigned short*)d_ws;                  // 8 MB
    unsigned short* Yb = Xb + (size_t)NROWS * D_DIM;             // 8 MB
    float* x2 = (float*)(Yb + (size_t)NROWS * D_DIM);            // 32 KB
    float* y2 = x2 + NROWS;                                      // 32 KB

    prep_all<<<2 * NROWS, 64, 0, stream>>>(X, Y, Xb, Yb, x2, y2);

    const int grid = (NROWS / BM) * (NROWS / BN);  // 1024
    rbf_gemm<<<grid, 512, 0, stream>>>(Xb, Yb, x2, y2, gamma, out);
}